// Round 14
// baseline (171.688 us; speedup 1.0000x reference)
//
#include <hip/hip_runtime.h>
#include <cstddef>
#include <cstdint>

#define NH 16
#define HD 64
#define NSEQ 1024
#define NB 4
#define DM 1024
#define SCALE 0.125f   // 64^-0.5 (folded into trig-table z slot)

typedef __attribute__((ext_vector_type(8))) short v8s;   // 8 bf16
typedef __attribute__((ext_vector_type(4))) float v4f;   // 4 f32

__device__ __forceinline__ short f2bf(float x) {
    union { float f; unsigned u; } v; v.f = x;
    unsigned r = v.u + 0x7FFF + ((v.u >> 16) & 1);
    return (short)(r >> 16);
}
__device__ __forceinline__ float bf2f(short x) {
    union { unsigned u; float f; } v; v.u = ((unsigned)(unsigned short)x) << 16;
    return v.f;
}
__device__ __forceinline__ void gload16(const void* g, void* l) {
    __builtin_amdgcn_global_load_lds(
        (const __attribute__((address_space(1))) void*)g,
        (__attribute__((address_space(3))) void*)l, 16, 0, 0);
}
__device__ __forceinline__ int gswz(int r, int kbyte) {
    return (r * 64 + kbyte) ^ (((r >> 1) & 3) << 4);
}
__device__ __forceinline__ int aswz(int r, int byte) {
    return (r * 128 + byte) ^ ((r & 7) << 4);
}
#define SBAR() __builtin_amdgcn_s_barrier()
#define WAITV0() asm volatile("s_waitcnt vmcnt(0)" ::: "memory")
#define WAITV4() asm volatile("s_waitcnt vmcnt(4)" ::: "memory")
#define WAITL() asm volatile("s_waitcnt lgkmcnt(0)" ::: "memory")

// ---- prep_inputs: [0,1280) tconv W->tiled bf16; [1280,1536) gamma+Xb; [1536,2048) trig table ----
__global__ __launch_bounds__(256) void prep_inputs(const float* __restrict__ X,
                                                   const float* __restrict__ ts,
                                                   const float* __restrict__ Wq,
                                                   const float* __restrict__ Wg,
                                                   const float* __restrict__ Wgt,
                                                   const float* __restrict__ Wo,
                                                   short* __restrict__ Wtq,
                                                   short* __restrict__ Wtg,
                                                   short* __restrict__ Wto,
                                                   float* __restrict__ loggam,
                                                   short* __restrict__ Xb,
                                                   float4* __restrict__ tbl) {
    __shared__ float smem[1024 * 17];
    const int bid = blockIdx.x;
    const int tid = threadIdx.x;
    if (bid < 1280) {
        short (*lsm)[136] = (short(*)[136])smem;
        int ct = bid % 40;
        const int kt = bid / 40;
        const float* W; short* Bt; int N;
        if (ct < 24)      { W = Wq;  Bt = Wtq; N = 3072; }
        else if (ct < 32) { W = Wgt; Bt = Wtg; N = 1024; ct -= 24; }
        else              { W = Wo;  Bt = Wto; N = 1024; ct -= 32; }
        {
            const int kk = tid >> 3, nn0 = (tid & 7) * 16;
            const float* src = W + (size_t)(kt * 32 + kk) * N + ct * 128 + nn0;
#pragma unroll
            for (int j = 0; j < 16; j += 4) {
                float4 v = *(const float4*)(src + j);
                lsm[kk][nn0 + j] = f2bf(v.x); lsm[kk][nn0 + j + 1] = f2bf(v.y);
                lsm[kk][nn0 + j + 2] = f2bf(v.z); lsm[kk][nn0 + j + 3] = f2bf(v.w);
            }
        }
        __syncthreads();
        const int rloc = tid >> 1, kb0 = (tid & 1) * 16;
        short o[16] __attribute__((aligned(16)));
#pragma unroll
        for (int j = 0; j < 16; ++j) o[j] = lsm[kb0 + j][rloc];
        char* base = (char*)(Bt + ((size_t)ct * 32 + kt) * 4096);
#pragma unroll
        for (int c = 0; c < 2; ++c)
            *(v8s*)(base + gswz(rloc, kb0 * 2 + c * 16)) = *(v8s*)&o[c * 8];
    } else if (bid < 1536) {
        float* wgs = smem;
#pragma unroll
        for (int it = 0; it < 16; ++it) {
            const int idx = it * 1024 + tid * 4;
            float4 v = *(const float4*)(Wg + idx);
            const int k = idx >> 4, h0 = idx & 15;
            wgs[k * 17 + h0]     = v.x;
            wgs[k * 17 + h0 + 1] = v.y;
            wgs[k * 17 + h0 + 2] = v.z;
            wgs[k * 17 + h0 + 3] = v.w;
        }
        __syncthreads();
        const int r = tid >> 4, c = tid & 15;
        const int row = (bid - 1280) * 16 + r;
        const int rt = row >> 7, rloc = row & 127;
        char* xtile = (char*)(Xb + (size_t)rt * 32 * 4096);
        const float* xrow = X + (size_t)row * DM;
        float acc[16];
#pragma unroll
        for (int h = 0; h < 16; ++h) acc[h] = 0.0f;
#pragma unroll 4
        for (int i = 0; i < 16; ++i) {
            const int kb = i * 64 + c * 4;
            float4 xv = *(const float4*)(xrow + kb);
            short4 o4 = make_short4(f2bf(xv.x), f2bf(xv.y), f2bf(xv.z), f2bf(xv.w));
            *(short4*)(xtile + (size_t)(kb >> 5) * 8192 + gswz(rloc, (kb & 31) * 2)) = o4;
            const float xs[4] = {xv.x, xv.y, xv.z, xv.w};
#pragma unroll
            for (int j = 0; j < 4; ++j) {
                const float* wrow = &wgs[(kb + j) * 17];
#pragma unroll
                for (int h = 0; h < 16; ++h) acc[h] = fmaf(xs[j], wrow[h], acc[h]);
            }
        }
#pragma unroll
        for (int h = 0; h < 16; ++h) {
#pragma unroll
            for (int off = 8; off >= 1; off >>= 1)
                acc[h] += __shfl_xor(acc[h], off, 16);
        }
        const float d = acc[c];
        const float sig = 1.0f / (1.0f + expf(-d));
        const float gam = powf(sig, 1.0f / 20.0f);
        loggam[(size_t)row * NH + c] = logf(gam + 1e-8f);
    } else {
        const int e = (bid - 1536) * 256 + tid;     // 131072 entries
        const int row = e >> 5, f = e & 31;
        const float tv = ts[row];
        const float inv_freq = exp2f(-0.4152410119f * (float)f);
        const float ang = tv * inv_freq;
        const float s = sinf(ang), c = cosf(ang);
        const float sv = ((float)(2 * f) + 25.6f) * (1.0f / 89.6f);
        const float ee = log2f(sv) * tv * (1.0f / 512.0f);
        tbl[e] = make_float4(c, s, exp2f(ee) * SCALE, exp2f(-ee));
    }
}

// ---------- bf16 MFMA GEMM on tiled inputs: C = A @ B^T, K=1024 ----------
// MODE 0: f32 row-major. MODE 1: bf16 row-major. MODE 2: fused gn+silu -> tiled bf16.
// MODE 3: direct V^T tile store into Vtb (aswz layout, uint2 packed).
template<int MODE>
__global__ __launch_bounds__(256) void gemm_tt(const short* __restrict__ A,
                                               const short* __restrict__ B,
                                               void* __restrict__ C, int N,
                                               const short* __restrict__ O,
                                               const float* __restrict__ partial) {
    __shared__ short As[4096];
    __shared__ short Bs[4096];
    const int tid = threadIdx.x;
    const int w = tid >> 6, l = tid & 63;
    const int wr = w >> 1, wc = w & 1;
    const int rt = blockIdx.y, ct = blockIdx.x;
    const char* Abase = (const char*)A + ((size_t)rt * 32) * 8192;
    const char* Bbase = (const char*)B + ((size_t)ct * 32) * 8192;

    v4f acc[4][4];
#pragma unroll
    for (int i = 0; i < 4; ++i)
#pragma unroll
        for (int j = 0; j < 4; ++j) acc[i][j] = (v4f){0.f, 0.f, 0.f, 0.f};

    for (int kt = 0; kt < 32; ++kt) {
        __syncthreads();
#pragma unroll
        for (int i = 0; i < 2; ++i) {
            const int c = w * 2 + i;
            gload16(Abase + (size_t)kt * 8192 + c * 1024 + l * 16, (char*)As + c * 1024);
            gload16(Bbase + (size_t)kt * 8192 + c * 1024 + l * 16, (char*)Bs + c * 1024);
        }
        __syncthreads();
        v8s af[4], bfr[4];
#pragma unroll
        for (int i = 0; i < 4; ++i) {
            const int ra = wr * 64 + i * 16 + (l & 15);
            af[i] = *(const v8s*)((char*)As + gswz(ra, (l >> 4) * 16));
            const int rb = wc * 64 + i * 16 + (l & 15);
            bfr[i] = *(const v8s*)((char*)Bs + gswz(rb, (l >> 4) * 16));
        }
#pragma unroll
        for (int i = 0; i < 4; ++i)
#pragma unroll
            for (int j = 0; j < 4; ++j)
                acc[i][j] = __builtin_amdgcn_mfma_f32_16x16x32_bf16(af[i], bfr[j], acc[i][j], 0, 0, 0);
    }
    float mu = 0.f, rstd = 0.f;
    if (MODE == 2) {
        const int hh = ct * 2 + wc;
        const int bh = (rt >> 3) * NH + hh;
        float s = 0.f, q = 0.f;
#pragma unroll
        for (int i = 0; i < 8; ++i) {
            s += partial[(bh * 8 + i) * 2];
            q += partial[(bh * 8 + i) * 2 + 1];
        }
        const float inv = 1.0f / (NSEQ * HD);
        mu = s * inv;
        rstd = rsqrtf(q * inv - mu * mu + 1e-5f);
    }
#pragma unroll
    for (int i = 0; i < 4; ++i)
#pragma unroll
        for (int j = 0; j < 4; ++j) {
            const int r0 = rt * 128 + wr * 64 + i * 16 + (l >> 4) * 4;
            const int cc = ct * 128 + wc * 64 + j * 16 + (l & 15);
            if (MODE == 3) {
                // V^T tile store: head h = ct*2+wc, d = j*16+(l&15), m rows = r0..r0+3
                const int h = ct * 2 + wc;
                const int d = j * 16 + (l & 15);
                const int b = r0 >> 10;
                const int tile = (r0 >> 6) & 15;
                const int m0 = r0 & 63;
                union { short s[4]; uint2 u; } pk;
#pragma unroll
                for (int t2 = 0; t2 < 4; ++t2) pk.s[t2] = f2bf(acc[i][j][t2]);
                char* base = (char*)C + ((size_t)((b * 16 + h) * 16 + tile)) * 8192;
                *(uint2*)(base + aswz(d, m0 * 2)) = pk.u;
                continue;
            }
#pragma unroll
            for (int t2 = 0; t2 < 4; ++t2) {
                if (MODE == 1) ((short*)C)[(size_t)(r0 + t2) * N + cc] = f2bf(acc[i][j][t2]);
                else if (MODE == 0) ((float*)C)[(size_t)(r0 + t2) * N + cc] = acc[i][j][t2];
                else if (MODE == 2) {
                    const int row = r0 + t2;
                    const float g = acc[i][j][t2];
                    const float silu = g / (1.0f + __expf(-g));
                    const float ov = bf2f(O[(size_t)row * DM + cc]);
                    const float val = silu * (ov - mu) * rstd;
                    const int rloc = row - rt * 128;
                    char* base = (char*)((short*)C + ((size_t)rt * 32 + (cc >> 5)) * 4096);
                    *(short*)(base + gswz(rloc, (cc & 31) * 2)) = f2bf(val);
                }
            }
        }
}

// -------- parallel cumsum over n per (b,h); writes TRANSPOSED [bh][n] ----------
__global__ __launch_bounds__(256) void scan_kernel(const float* __restrict__ lg,
                                                   float* __restrict__ lgT) {
    const int wave = threadIdx.x >> 6;
    const int lane = threadIdx.x & 63;
    const int bh = blockIdx.x * 4 + wave;
    const int b = bh >> 4, h = bh & 15;
    const float* p = lg + (size_t)b * NSEQ * NH + h;
    const int n0 = lane * 16;
    float v[16];
    float s = 0.0f;
#pragma unroll
    for (int j = 0; j < 16; ++j) { v[j] = p[(size_t)(n0 + j) * NH]; s += v[j]; }
    float sc = s;
#pragma unroll
    for (int off = 1; off < 64; off <<= 1) {
        float o = __shfl_up(sc, off, 64);
        if (lane >= off) sc += o;
    }
    float acc = sc - s;
    float* q = lgT + (size_t)bh * NSEQ + n0;
#pragma unroll
    for (int j = 0; j < 16; ++j) { acc += v[j]; q[j] = acc; }
}

// ---- prep: qkvb bf16 (Q,K only; stride 2048) -> RoPE'd Q(*SCALE)/K tiles ----
__global__ __launch_bounds__(256) void prep(const short* __restrict__ qkvb,
                                            const float4* __restrict__ tbl,
                                            short* __restrict__ Qb,
                                            short* __restrict__ Kb) {
    const int tile = blockIdx.x, bh = blockIdx.y;
    const int b = bh >> 4, h = bh & 15;
    const int t = threadIdx.x;
    const int rloc = t >> 2, d0 = (t & 3) * 16;
    const int row = b * NSEQ + tile * 64 + rloc;
    const short* src = qkvb + (size_t)row * 2048 + h * HD;
    const size_t tb = ((size_t)bh * 16 + tile) * 4096;

    float qa[16], ka[16];
    {
        v8s q0 = *(const v8s*)(src + d0), q1 = *(const v8s*)(src + d0 + 8);
        v8s k0 = *(const v8s*)(src + 1024 + d0), k1 = *(const v8s*)(src + 1024 + d0 + 8);
#pragma unroll
        for (int j = 0; j < 8; ++j) {
            qa[j] = bf2f(q0[j]); qa[j + 8] = bf2f(q1[j]);
            ka[j] = bf2f(k0[j]); ka[j + 8] = bf2f(k1[j]);
        }
    }
    short qo[16] __attribute__((aligned(16)));
    short ko[16] __attribute__((aligned(16)));
#pragma unroll
    for (int j = 0; j < 8; ++j) {
        const int i = (d0 >> 1) + j;
        const float4 T = tbl[row * 32 + i];
        const float c = T.x, s = T.y, sc = T.z, isc = T.w;
        qo[2 * j]     = f2bf((qa[2 * j] * c - qa[2 * j + 1] * s) * sc);
        qo[2 * j + 1] = f2bf((qa[2 * j + 1] * c + qa[2 * j] * s) * sc);
        ko[2 * j]     = f2bf((ka[2 * j] * c - ka[2 * j + 1] * s) * isc);
        ko[2 * j + 1] = f2bf((ka[2 * j + 1] * c + ka[2 * j] * s) * isc);
    }
#pragma unroll
    for (int c = 0; c < 2; ++c) {
        *(v8s*)((char*)(Qb + tb) + aswz(rloc, d0 * 2 + c * 16)) = *(v8s*)&qo[c * 8];
        *(v8s*)((char*)(Kb + tb) + aswz(rloc, d0 * 2 + c * 16)) = *(v8s*)&ko[c * 8];
    }
}

// -- attn7: 3-buffer K/V rotation, ONE barrier/visit (issue-after-barrier),
//    2-deep prefetch, swapped-operand MFMA, setprio, bf16 O, fused GN partials --
__global__ __launch_bounds__(256) void attn7(const short* __restrict__ Qb,
                                             const short* __restrict__ Kb,
                                             const short* __restrict__ Vtb,
                                             const float* __restrict__ logbT,
                                             short* __restrict__ O,
                                             float* __restrict__ partial) {
    __shared__ short KV[3][2][4096];  // [buf][K=0/V=1][8KB]
    __shared__ short Ps[8192];        // P tiles; also Q staging (16KB)
    __shared__ float lbAll[1024];
    __shared__ float emAll[1024];
    const int id = blockIdx.x;
    const int half = id >> 8;
    const int idx = id & 255;
    const int bh = ((idx & 7) << 3) | ((idx >> 3) & 7);
    const int qq = half == 0 ? (4 + (idx >> 6)) : (3 - (idx >> 6));
    const int b = bh >> 4, h = bh & 15;
    const int tid = threadIdx.x;
    const int w = tid >> 6, l = tid & 63;
    const int n0 = qq * 128;
    const int NT = 2 * qq + 2;

#pragma unroll
    for (int i = 0; i < 4; ++i) {
        const int c = w * 4 + i;
        gload16((const char*)Qb + ((size_t)bh * 16 + 2 * qq) * 8192 + c * 1024 + l * 16,
                (char*)Ps + c * 1024);
    }
    for (int i = tid; i < 1024; i += 256)
        lbAll[i] = logbT[(size_t)bh * NSEQ + i];
    WAITV0(); WAITL();
    SBAR();

    const float base = lbAll[n0];
    for (int i = tid; i < NT * 64; i += 256) emAll[i] = __expf(base - lbAll[i]);
    float en[2];
#pragma unroll
    for (int rg = 0; rg < 2; ++rg)
        en[rg] = __expf(lbAll[n0 + w * 32 + rg * 16 + (l & 15)] - base);
    v8s aq[2][2];
#pragma unroll
    for (int rg = 0; rg < 2; ++rg)
#pragma unroll
        for (int kc = 0; kc < 2; ++kc) {
            const int r = w * 32 + rg * 16 + (l & 15);
            aq[rg][kc] = *(const v8s*)((char*)Ps + (r >> 6) * 8192 +
                                       aswz(r & 63, kc * 64 + (l >> 4) * 16));
        }
    WAITL();
    SBAR();   // emAll visible; Ps free for P use

    v4f oacc[2][4];
#pragma unroll
    for (int rg = 0; rg < 2; ++rg)
#pragma unroll
        for (int dt = 0; dt < 4; ++dt) oacc[rg][dt] = (v4f){0.f, 0.f, 0.f, 0.f};

    // prologue: prefetch tiles 0 and 1 (NT >= 2 always)
#pragma unroll
    for (int tt = 0; tt < 2; ++tt) {
#pragma unroll
        for (int i = 0; i < 2; ++i) {
            const int c = w * 2 + i;
            gload16((const char*)Kb + ((size_t)bh * 16 + tt) * 8192 + c * 1024 + l * 16,
                    (char*)KV[tt][0] + c * 1024);
            gload16((const char*)Vtb + ((size_t)bh * 16 + tt) * 8192 + c * 1024 + l * 16,
                    (char*)KV[tt][1] + c * 1024);
        }
    }

    for (int t = 0; t < NT; ++t) {
        const int m0 = t * 64;
        const int buf = t % 3;
        if (t + 1 < NT) { WAITV4(); } else { WAITV0(); }
        SBAR();   // tile t fully staged by all waves; prev compute (t-1) done
        if (t + 2 < NT) {
            const int nb = (t + 2) % 3;
#pragma unroll
            for (int i = 0; i < 2; ++i) {
                const int c = w * 2 + i;
                gload16((const char*)Kb + ((size_t)bh * 16 + t + 2) * 8192 + c * 1024 + l * 16,
                        (char*)KV[nb][0] + c * 1024);
                gload16((const char*)Vtb + ((size_t)bh * 16 + t + 2) * 8192 + c * 1024 + l * 16,
                        (char*)KV[nb][1] + c * 1024);
            }
        }

        const bool active = (m0 <= n0 + w * 32 + 31);
        if (active) {
            const char* KsB = (const char*)KV[buf][0];
            const char* VtsB = (const char*)KV[buf][1];
            v4f sfr[2][4];
#pragma unroll
            for (int rg = 0; rg < 2; ++rg)
#pragma unroll
                for (int m4 = 0; m4 < 4; ++m4) sfr[rg][m4] = (v4f){0.f, 0.f, 0.f, 0.f};
            __builtin_amdgcn_s_setprio(1);
#pragma unroll
            for (int m4 = 0; m4 < 4; ++m4) {
#pragma unroll
                for (int kc = 0; kc < 2; ++kc) {
                    const int m = m4 * 16 + (l & 15);
                    v8s bk = *(const v8s*)(KsB + aswz(m, kc * 64 + (l >> 4) * 16));
#pragma unroll
                    for (int rg = 0; rg < 2; ++rg)
                        sfr[rg][m4] = __builtin_amdgcn_mfma_f32_16x16x32_bf16(bk, aq[rg][kc], sfr[rg][m4], 0, 0, 0);
                }
            }
            __builtin_amdgcn_s_setprio(0);
            const bool needMask = (m0 + 63) > (n0 + w * 32);
#pragma unroll
            for (int rg = 0; rg < 2; ++rg) {
                const int r = w * 32 + rg * 16 + (l & 15);
                const float enr = en[rg];
#pragma unroll
                for (int m4 = 0; m4 < 4; ++m4) {
                    const int mbase = m0 + m4 * 16 + (l >> 4) * 4;
                    float4 emv = *(const float4*)&emAll[mbase];
                    const float ems[4] = {emv.x, emv.y, emv.z, emv.w};
                    union { short s[4]; uint2 u; } pk;
#pragma unroll
                    for (int t2 = 0; t2 < 4; ++t2) {
                        float sval = sfr[rg][m4][t2] * enr * ems[t2];
                        if (needMask && (n0 + r) < (mbase + t2)) sval = 0.0f;
                        pk.s[t2] = f2bf(sval);
                    }
                    *(uint2*)((char*)Ps + aswz(r, (m4 * 16 + (l >> 4) * 4) * 2)) = pk.u;
                }
            }
            WAITL();
            __builtin_amdgcn_sched_barrier(0);
            __builtin_amdgcn_s_setprio(1);
#pragma unroll
            for (int kc = 0; kc < 2; ++kc) {
                v8s ap[2];
#pragma unroll
                for (int rg = 0; rg < 2; ++rg) {
                    const int r = w * 32 + rg * 16 + (l & 15);
                    ap[rg] = *(const v8s*)((char*)Ps + aswz(r, kc * 64 + (l >> 4) * 16));
                }
#pragma unroll
                for (int dt = 0; dt < 4; ++dt) {
                    const int d = dt * 16 + (l & 15);
                    v8s bv = *(const v8s*)(VtsB + aswz(d, kc * 64 + (l >> 4) * 16));
#pragma unroll
                    for (int rg = 0; rg < 2; ++rg)
                        oacc[rg][dt] = __builtin_amdgcn_mfma_f32_16x16x32_bf16(bv, ap[rg], oacc[rg][dt], 0, 0, 0);
                }
            }
            __builtin_amdgcn_s_setprio(0);
        }
    }
    float psum = 0.0f, pssq = 0.0f;
#pragma unroll
    for (int rg = 0; rg < 2; ++rg) {
        const int row = n0 + w * 32 + rg * 16 + (l & 15);
#pragma unroll
        for (int dt = 0; dt < 4; ++dt) {
            const float a0 = oacc[rg][dt][0], a1 = oacc[rg][dt][1];
            const float a2 = oacc[rg][dt][2], a3 = oacc[rg][dt][3];
            short4 o4 = make_short4(f2bf(a0), f2bf(a1), f2bf(a2), f2bf(a3));
            *(short4*)(O + (size_t)(b * NSEQ + row) * DM + h * HD + dt * 16 + (l >> 4) * 4) = o4;
            psum += a0 + a1 + a2 + a3;
            pssq += a0 * a0 + a1 * a1 + a2 * a2 + a3 * a3;
        }
    }
    __syncthreads();
    float* red = (float*)KV;
    red[tid] = psum; red[256 + tid] = pssq;
    __syncthreads();
    for (int s = 128; s > 0; s >>= 1) {
        if (tid < s) { red[tid] += red[tid + s]; red[256 + tid] += red[256 + tid + s]; }
        __syncthreads();
    }
    if (tid == 0) {
        partial[(bh * 8 + qq) * 2]     = red[0];
        partial[(bh * 8 + qq) * 2 + 1] = red[256];
    }
}

extern "C" void kernel_launch(void* const* d_in, const int* in_sizes, int n_in,
                              void* d_out, int out_size, void* d_ws, size_t ws_size,
                              hipStream_t stream) {
    const float* X       = (const float*)d_in[0];
    const float* ts      = (const float*)d_in[1];
    const float* W_qkv   = (const float*)d_in[2];
    const float* W_gamma = (const float*)d_in[3];
    const float* W_gated = (const float*)d_in[4];
    const float* W_out   = (const float*)d_in[5];
    float* out = (float*)d_out;

    char* ws = (char*)d_ws;
    short*  Xb    = (short*)(ws + 0);              //  8 MB (tiled bf16)
    short*  Wtq   = (short*)(ws + 8388608);        //  6 MB
    short*  Wtg   = (short*)(ws + 14680064);       //  2 MB
    short*  Wto   = (short*)(ws + 16777216);       //  2 MB
    short*  Qb    = (short*)(ws + 18874368);       //  8 MB
    short*  Kb    = (short*)(ws + 27262976);       //  8 MB
    short*  Vtb   = (short*)(ws + 35651584);       //  8 MB
    float*  logb  = (float*)(ws + 44040192);       //  256 KB
    float*  logbT = (float*)(ws + 44302336);       //  256 KB
    float4* tbl   = (float4*)(ws + 44564480);      //  2 MB
    short*  Oatt  = (short*)(ws + 46661632);       //  8 MB (bf16)
    float*  partial = (float*)(ws + 55050240);     //  4 KB
    short*  Gb    = (short*)(ws + 55054336);       //  8 MB
    short*  qkvb  = (short*)(ws + 63442944);       // 16 MB (Q,K only; stride 2048)

    prep_inputs<<<2048, 256, 0, stream>>>(X, ts, W_qkv, W_gamma, W_gated, W_out,
                                          Wtq, Wtg, Wto, logb, Xb, tbl);
    scan_kernel<<<16, 256, 0, stream>>>(logb, logbT);
    gemm_tt<1><<<dim3(16, 32), 256, 0, stream>>>(Xb, Wtq, qkvb, 2048, nullptr, nullptr);
    gemm_tt<3><<<dim3(8, 32), 256, 0, stream>>>(Xb, Wtq + (size_t)16 * 32 * 4096, Vtb, 1024,
                                                nullptr, nullptr);
    prep<<<dim3(16, 64), 256, 0, stream>>>(qkvb, tbl, Qb, Kb);
    attn7<<<512, 256, 0, stream>>>(Qb, Kb, Vtb, logbT, Oatt, partial);
    gemm_tt<2><<<dim3(8, 32), 256, 0, stream>>>(Xb, Wtg, Gb, 1024, Oatt, partial);
    gemm_tt<0><<<dim3(8, 32), 256, 0, stream>>>(Gb, Wto, out, 1024, nullptr, nullptr);
}

// Round 15
// 153.032 us; speedup vs baseline: 1.1219x; 1.1219x over previous
//
#include <hip/hip_runtime.h>
#include <cstddef>
#include <cstdint>

#define NH 16
#define HD 64
#define NSEQ 1024
#define NB 4
#define DM 1024
#define SCALE 0.125f   // 64^-0.5 (folded into trig-table z slot)

typedef __attribute__((ext_vector_type(8))) short v8s;   // 8 bf16
typedef __attribute__((ext_vector_type(4))) float v4f;   // 4 f32

__device__ __forceinline__ short f2bf(float x) {
    union { float f; unsigned u; } v; v.f = x;
    unsigned r = v.u + 0x7FFF + ((v.u >> 16) & 1);
    return (short)(r >> 16);
}
__device__ __forceinline__ float bf2f(short x) {
    union { unsigned u; float f; } v; v.u = ((unsigned)(unsigned short)x) << 16;
    return v.f;
}
__device__ __forceinline__ void gload16(const void* g, void* l) {
    __builtin_amdgcn_global_load_lds(
        (const __attribute__((address_space(1))) void*)g,
        (__attribute__((address_space(3))) void*)l, 16, 0, 0);
}
__device__ __forceinline__ int gswz(int r, int kbyte) {
    return (r * 64 + kbyte) ^ (((r >> 1) & 3) << 4);
}
__device__ __forceinline__ int aswz(int r, int byte) {
    return (r * 128 + byte) ^ ((r & 7) << 4);
}
#define SBAR() __builtin_amdgcn_s_barrier()
#define WAITV0() asm volatile("s_waitcnt vmcnt(0)" ::: "memory")
#define WAITV4() asm volatile("s_waitcnt vmcnt(4)" ::: "memory")
#define WAITL() asm volatile("s_waitcnt lgkmcnt(0)" ::: "memory")

// ---- prep_inputs: [0,1280) tconv W->tiled bf16; [1280,1536) gamma+Xb; [1536,2048) trig table ----
__global__ __launch_bounds__(256) void prep_inputs(const float* __restrict__ X,
                                                   const float* __restrict__ ts,
                                                   const float* __restrict__ Wq,
                                                   const float* __restrict__ Wg,
                                                   const float* __restrict__ Wgt,
                                                   const float* __restrict__ Wo,
                                                   short* __restrict__ Wtq,
                                                   short* __restrict__ Wtg,
                                                   short* __restrict__ Wto,
                                                   float* __restrict__ loggam,
                                                   short* __restrict__ Xb,
                                                   float4* __restrict__ tbl) {
    __shared__ float smem[1024 * 17];
    const int bid = blockIdx.x;
    const int tid = threadIdx.x;
    if (bid < 1280) {
        short (*lsm)[136] = (short(*)[136])smem;
        int ct = bid % 40;
        const int kt = bid / 40;
        const float* W; short* Bt; int N;
        if (ct < 24)      { W = Wq;  Bt = Wtq; N = 3072; }
        else if (ct < 32) { W = Wgt; Bt = Wtg; N = 1024; ct -= 24; }
        else              { W = Wo;  Bt = Wto; N = 1024; ct -= 32; }
        {
            const int kk = tid >> 3, nn0 = (tid & 7) * 16;
            const float* src = W + (size_t)(kt * 32 + kk) * N + ct * 128 + nn0;
#pragma unroll
            for (int j = 0; j < 16; j += 4) {
                float4 v = *(const float4*)(src + j);
                lsm[kk][nn0 + j] = f2bf(v.x); lsm[kk][nn0 + j + 1] = f2bf(v.y);
                lsm[kk][nn0 + j + 2] = f2bf(v.z); lsm[kk][nn0 + j + 3] = f2bf(v.w);
            }
        }
        __syncthreads();
        const int rloc = tid >> 1, kb0 = (tid & 1) * 16;
        short o[16] __attribute__((aligned(16)));
#pragma unroll
        for (int j = 0; j < 16; ++j) o[j] = lsm[kb0 + j][rloc];
        char* base = (char*)(Bt + ((size_t)ct * 32 + kt) * 4096);
#pragma unroll
        for (int c = 0; c < 2; ++c)
            *(v8s*)(base + gswz(rloc, kb0 * 2 + c * 16)) = *(v8s*)&o[c * 8];
    } else if (bid < 1536) {
        float* wgs = smem;
#pragma unroll
        for (int it = 0; it < 16; ++it) {
            const int idx = it * 1024 + tid * 4;
            float4 v = *(const float4*)(Wg + idx);
            const int k = idx >> 4, h0 = idx & 15;
            wgs[k * 17 + h0]     = v.x;
            wgs[k * 17 + h0 + 1] = v.y;
            wgs[k * 17 + h0 + 2] = v.z;
            wgs[k * 17 + h0 + 3] = v.w;
        }
        __syncthreads();
        const int r = tid >> 4, c = tid & 15;
        const int row = (bid - 1280) * 16 + r;
        const int rt = row >> 7, rloc = row & 127;
        char* xtile = (char*)(Xb + (size_t)rt * 32 * 4096);
        const float* xrow = X + (size_t)row * DM;
        float acc[16];
#pragma unroll
        for (int h = 0; h < 16; ++h) acc[h] = 0.0f;
#pragma unroll 4
        for (int i = 0; i < 16; ++i) {
            const int kb = i * 64 + c * 4;
            float4 xv = *(const float4*)(xrow + kb);
            short4 o4 = make_short4(f2bf(xv.x), f2bf(xv.y), f2bf(xv.z), f2bf(xv.w));
            *(short4*)(xtile + (size_t)(kb >> 5) * 8192 + gswz(rloc, (kb & 31) * 2)) = o4;
            const float xs[4] = {xv.x, xv.y, xv.z, xv.w};
#pragma unroll
            for (int j = 0; j < 4; ++j) {
                const float* wrow = &wgs[(kb + j) * 17];
#pragma unroll
                for (int h = 0; h < 16; ++h) acc[h] = fmaf(xs[j], wrow[h], acc[h]);
            }
        }
#pragma unroll
        for (int h = 0; h < 16; ++h) {
#pragma unroll
            for (int off = 8; off >= 1; off >>= 1)
                acc[h] += __shfl_xor(acc[h], off, 16);
        }
        const float d = acc[c];
        const float sig = 1.0f / (1.0f + expf(-d));
        const float gam = powf(sig, 1.0f / 20.0f);
        loggam[(size_t)row * NH + c] = logf(gam + 1e-8f);
    } else {
        // ---- trig table: tbl[row*32+f] = (cos, sin, exp2(e)*SCALE, exp2(-e)) ----
        const int e = (bid - 1536) * 256 + tid;     // 131072 entries
        const int row = e >> 5, f = e & 31;
        const float tv = ts[row];
        const float inv_freq = exp2f(-0.4152410119f * (float)f);
        const float ang = tv * inv_freq;
        const float s = sinf(ang), c = cosf(ang);
        const float sv = ((float)(2 * f) + 25.6f) * (1.0f / 89.6f);
        const float ee = log2f(sv) * tv * (1.0f / 512.0f);
        tbl[e] = make_float4(c, s, exp2f(ee) * SCALE, exp2f(-ee));
    }
}

// ---------- bf16 MFMA GEMM on tiled inputs: C = A @ B^T, K=1024 ----------
// MODE 0: f32 row-major out. MODE 1: bf16 row-major out.
// MODE 2: fused gn-stats + silu(acc)*groupnorm(Obf16) -> bf16 tiled-swizzled (N=1024).
template<int MODE>
__global__ __launch_bounds__(256) void gemm_tt(const short* __restrict__ A,
                                               const short* __restrict__ B,
                                               void* __restrict__ C, int N,
                                               const short* __restrict__ O,
                                               const float* __restrict__ partial) {
    __shared__ short As[4096];
    __shared__ short Bs[4096];
    const int tid = threadIdx.x;
    const int w = tid >> 6, l = tid & 63;
    const int wr = w >> 1, wc = w & 1;
    const int rt = blockIdx.y, ct = blockIdx.x;
    const char* Abase = (const char*)A + ((size_t)rt * 32) * 8192;
    const char* Bbase = (const char*)B + ((size_t)ct * 32) * 8192;

    v4f acc[4][4];
#pragma unroll
    for (int i = 0; i < 4; ++i)
#pragma unroll
        for (int j = 0; j < 4; ++j) acc[i][j] = (v4f){0.f, 0.f, 0.f, 0.f};

    for (int kt = 0; kt < 32; ++kt) {
        __syncthreads();
#pragma unroll
        for (int i = 0; i < 2; ++i) {
            const int c = w * 2 + i;
            gload16(Abase + (size_t)kt * 8192 + c * 1024 + l * 16, (char*)As + c * 1024);
            gload16(Bbase + (size_t)kt * 8192 + c * 1024 + l * 16, (char*)Bs + c * 1024);
        }
        __syncthreads();
        v8s af[4], bfr[4];
#pragma unroll
        for (int i = 0; i < 4; ++i) {
            const int ra = wr * 64 + i * 16 + (l & 15);
            af[i] = *(const v8s*)((char*)As + gswz(ra, (l >> 4) * 16));
            const int rb = wc * 64 + i * 16 + (l & 15);
            bfr[i] = *(const v8s*)((char*)Bs + gswz(rb, (l >> 4) * 16));
        }
#pragma unroll
        for (int i = 0; i < 4; ++i)
#pragma unroll
            for (int j = 0; j < 4; ++j)
                acc[i][j] = __builtin_amdgcn_mfma_f32_16x16x32_bf16(af[i], bfr[j], acc[i][j], 0, 0, 0);
    }
    float mu = 0.f, rstd = 0.f;
    if (MODE == 2) {
        const int hh = ct * 2 + wc;           // head is wave-constant
        const int bh = (rt >> 3) * NH + hh;
        float s = 0.f, q = 0.f;
#pragma unroll
        for (int i = 0; i < 8; ++i) {
            s += partial[(bh * 8 + i) * 2];
            q += partial[(bh * 8 + i) * 2 + 1];
        }
        const float inv = 1.0f / (NSEQ * HD);
        mu = s * inv;
        rstd = rsqrtf(q * inv - mu * mu + 1e-5f);
    }
#pragma unroll
    for (int i = 0; i < 4; ++i)
#pragma unroll
        for (int j = 0; j < 4; ++j) {
            const int r0 = rt * 128 + wr * 64 + i * 16 + (l >> 4) * 4;
            const int cc = ct * 128 + wc * 64 + j * 16 + (l & 15);
#pragma unroll
            for (int t2 = 0; t2 < 4; ++t2) {
                if (MODE == 1) ((short*)C)[(size_t)(r0 + t2) * N + cc] = f2bf(acc[i][j][t2]);
                else if (MODE == 0) ((float*)C)[(size_t)(r0 + t2) * N + cc] = acc[i][j][t2];
                else {
                    const int row = r0 + t2;
                    const float g = acc[i][j][t2];
                    const float silu = g / (1.0f + __expf(-g));
                    const float ov = bf2f(O[(size_t)row * DM + cc]);
                    const float val = silu * (ov - mu) * rstd;
                    const int rloc = row - rt * 128;
                    char* base = (char*)((short*)C + ((size_t)rt * 32 + (cc >> 5)) * 4096);
                    *(short*)(base + gswz(rloc, (cc & 31) * 2)) = f2bf(val);
                }
            }
        }
}

// -------- parallel cumsum over n per (b,h); writes TRANSPOSED [bh][n] ----------
__global__ __launch_bounds__(256) void scan_kernel(const float* __restrict__ lg,
                                                   float* __restrict__ lgT) {
    const int wave = threadIdx.x >> 6;
    const int lane = threadIdx.x & 63;
    const int bh = blockIdx.x * 4 + wave;
    const int b = bh >> 4, h = bh & 15;
    const float* p = lg + (size_t)b * NSEQ * NH + h;
    const int n0 = lane * 16;
    float v[16];
    float s = 0.0f;
#pragma unroll
    for (int j = 0; j < 16; ++j) { v[j] = p[(size_t)(n0 + j) * NH]; s += v[j]; }
    float sc = s;
#pragma unroll
    for (int off = 1; off < 64; off <<= 1) {
        float o = __shfl_up(sc, off, 64);
        if (lane >= off) sc += o;
    }
    float acc = sc - s;
    float* q = lgT + (size_t)bh * NSEQ + n0;
#pragma unroll
    for (int j = 0; j < 16; ++j) { acc += v[j]; q[j] = acc; }
}

// ---- prep: qkvb bf16 -> RoPE'd Q(*SCALE)/K + V^T tiles, trig from table ----
__global__ __launch_bounds__(256) void prep(const short* __restrict__ qkvb,
                                            const float4* __restrict__ tbl,
                                            short* __restrict__ Qb,
                                            short* __restrict__ Kb,
                                            short* __restrict__ Vtb) {
    __shared__ short vsm[64][72];
    const int tile = blockIdx.x, bh = blockIdx.y;
    const int b = bh >> 4, h = bh & 15;
    const int t = threadIdx.x;
    const int rloc = t >> 2, d0 = (t & 3) * 16;
    const int row = b * NSEQ + tile * 64 + rloc;
    const short* src = qkvb + (size_t)row * 3072 + h * HD;
    const size_t tb = ((size_t)bh * 16 + tile) * 4096;

    float qa[16], ka[16];
    {
        v8s q0 = *(const v8s*)(src + d0), q1 = *(const v8s*)(src + d0 + 8);
        v8s k0 = *(const v8s*)(src + 1024 + d0), k1 = *(const v8s*)(src + 1024 + d0 + 8);
#pragma unroll
        for (int j = 0; j < 8; ++j) {
            qa[j] = bf2f(q0[j]); qa[j + 8] = bf2f(q1[j]);
            ka[j] = bf2f(k0[j]); ka[j + 8] = bf2f(k1[j]);
        }
    }
    short qo[16] __attribute__((aligned(16)));
    short ko[16] __attribute__((aligned(16)));
#pragma unroll
    for (int j = 0; j < 8; ++j) {
        const int i = (d0 >> 1) + j;
        const float4 T = tbl[row * 32 + i];
        const float c = T.x, s = T.y, sc = T.z, isc = T.w;
        qo[2 * j]     = f2bf((qa[2 * j] * c - qa[2 * j + 1] * s) * sc);
        qo[2 * j + 1] = f2bf((qa[2 * j + 1] * c + qa[2 * j] * s) * sc);
        ko[2 * j]     = f2bf((ka[2 * j] * c - ka[2 * j + 1] * s) * isc);
        ko[2 * j + 1] = f2bf((ka[2 * j + 1] * c + ka[2 * j] * s) * isc);
    }
#pragma unroll
    for (int c = 0; c < 2; ++c) {
        *(v8s*)((char*)(Qb + tb) + aswz(rloc, d0 * 2 + c * 16)) = *(v8s*)&qo[c * 8];
        *(v8s*)((char*)(Kb + tb) + aswz(rloc, d0 * 2 + c * 16)) = *(v8s*)&ko[c * 8];
    }
    {
        v8s v0 = *(const v8s*)(src + 2048 + d0), v1 = *(const v8s*)(src + 2048 + d0 + 8);
        *(short4*)&vsm[rloc][d0]      = *(short4*)&v0;
        *(short4*)&vsm[rloc][d0 + 4]  = *((short4*)&v0 + 1);
        *(short4*)&vsm[rloc][d0 + 8]  = *(short4*)&v1;
        *(short4*)&vsm[rloc][d0 + 12] = *((short4*)&v1 + 1);
    }
    __syncthreads();
    {
        const int d = t >> 2, m0 = (t & 3) * 16;
        short vt[16] __attribute__((aligned(16)));
#pragma unroll
        for (int j = 0; j < 16; ++j) vt[j] = vsm[m0 + j][d];
#pragma unroll
        for (int c = 0; c < 2; ++c)
            *(v8s*)((char*)(Vtb + tb) + aswz(d, m0 * 2 + c * 16)) = *(v8s*)&vt[c * 8];
    }
}

// -- attn6: swapped-operand MFMA (S^T / O^T), setprio, bf16 O, fused GN partials --
__global__ __launch_bounds__(256) void attn6(const short* __restrict__ Qb,
                                             const short* __restrict__ Kb,
                                             const short* __restrict__ Vtb,
                                             const float* __restrict__ logbT,
                                             short* __restrict__ O,
                                             float* __restrict__ partial) {
    __shared__ short Ks[2][4096];
    __shared__ short Vts[2][4096];
    __shared__ short Ps[8192];       // P tiles; also Q staging (16KB)
    __shared__ float lbAll[1024];
    __shared__ float emAll[1024];
    const int id = blockIdx.x;
    const int half = id >> 8;                            // 0 = heavy, 1 = light
    const int idx = id & 255;
    const int bh = ((idx & 7) << 3) | ((idx >> 3) & 7);  // same bh & XCD for (i, i+256)
    const int qq = half == 0 ? (4 + (idx >> 6)) : (3 - (idx >> 6));
    const int b = bh >> 4, h = bh & 15;
    const int tid = threadIdx.x;
    const int w = tid >> 6, l = tid & 63;
    const int n0 = qq * 128;
    const int NT = 2 * qq + 2;

#pragma unroll
    for (int i = 0; i < 4; ++i) {
        const int c = w * 4 + i;
        gload16((const char*)Qb + ((size_t)bh * 16 + 2 * qq) * 8192 + c * 1024 + l * 16,
                (char*)Ps + c * 1024);
    }
    for (int i = tid; i < 1024; i += 256)
        lbAll[i] = logbT[(size_t)bh * NSEQ + i];
    WAITV0(); WAITL();
    SBAR();

    const float base = lbAll[n0];
    for (int i = tid; i < NT * 64; i += 256) emAll[i] = __expf(base - lbAll[i]);
    float en[2];
#pragma unroll
    for (int rg = 0; rg < 2; ++rg)
        en[rg] = __expf(lbAll[n0 + w * 32 + rg * 16 + (l & 15)] - base);
    v8s aq[2][2];
#pragma unroll
    for (int rg = 0; rg < 2; ++rg)
#pragma unroll
        for (int kc = 0; kc < 2; ++kc) {
            const int r = w * 32 + rg * 16 + (l & 15);
            aq[rg][kc] = *(const v8s*)((char*)Ps + (r >> 6) * 8192 +
                                       aswz(r & 63, kc * 64 + (l >> 4) * 16));
        }
    WAITL();
    SBAR();   // emAll visible; Ps free for P use

    v4f oacc[2][4];
#pragma unroll
    for (int rg = 0; rg < 2; ++rg)
#pragma unroll
        for (int dt = 0; dt < 4; ++dt) oacc[rg][dt] = (v4f){0.f, 0.f, 0.f, 0.f};

#pragma unroll
    for (int i = 0; i < 2; ++i) {
        const int c = w * 2 + i;
        gload16((const char*)Kb + ((size_t)bh * 16 + 0) * 8192 + c * 1024 + l * 16,
                (char*)Ks + c * 1024);
        gload16((const char*)Vtb + ((size_t)bh * 16 + 0) * 8192 + c * 1024 + l * 16,
                (char*)Vts + c * 1024);
    }

    for (int t = 0; t < NT; ++t) {
        const int m0 = t * 64;
        const int buf = t & 1;
        SBAR();
        if (t + 1 < NT) {
            const int nb = (t + 1) & 1;
#pragma unroll
            for (int i = 0; i < 2; ++i) {
                const int c = w * 2 + i;
                gload16((const char*)Kb + ((size_t)bh * 16 + t + 1) * 8192 + c * 1024 + l * 16,
                        (char*)Ks + nb * 8192 + c * 1024);
                gload16((const char*)Vtb + ((size_t)bh * 16 + t + 1) * 8192 + c * 1024 + l * 16,
                        (char*)Vts + nb * 8192 + c * 1024);
            }
            WAITV4();
        } else {
            WAITV0();
        }
        SBAR();

        const bool active = (m0 <= n0 + w * 32 + 31);
        if (active) {
            const char* KsB = (const char*)Ks + buf * 8192;
            const char* VtsB = (const char*)Vts + buf * 8192;
            v4f sfr[2][4];
#pragma unroll
            for (int rg = 0; rg < 2; ++rg)
#pragma unroll
                for (int m4 = 0; m4 < 4; ++m4) sfr[rg][m4] = (v4f){0.f, 0.f, 0.f, 0.f};
            __builtin_amdgcn_s_setprio(1);
#pragma unroll
            for (int m4 = 0; m4 < 4; ++m4) {
#pragma unroll
                for (int kc = 0; kc < 2; ++kc) {
                    const int m = m4 * 16 + (l & 15);
                    v8s bk = *(const v8s*)(KsB + aswz(m, kc * 64 + (l >> 4) * 16));
#pragma unroll
                    for (int rg = 0; rg < 2; ++rg)
                        sfr[rg][m4] = __builtin_amdgcn_mfma_f32_16x16x32_bf16(bk, aq[rg][kc], sfr[rg][m4], 0, 0, 0);
                }
            }
            __builtin_amdgcn_s_setprio(0);
            const bool needMask = (m0 + 63) > (n0 + w * 32);
#pragma unroll
            for (int rg = 0; rg < 2; ++rg) {
                const int r = w * 32 + rg * 16 + (l & 15);
                const float enr = en[rg];
#pragma unroll
                for (int m4 = 0; m4 < 4; ++m4) {
                    const int mbase = m0 + m4 * 16 + (l >> 4) * 4;
                    float4 emv = *(const float4*)&emAll[mbase];
                    const float ems[4] = {emv.x, emv.y, emv.z, emv.w};
                    union { short s[4]; uint2 u; } pk;
#pragma unroll
                    for (int t2 = 0; t2 < 4; ++t2) {
                        float sval = sfr[rg][m4][t2] * enr * ems[t2];
                        if (needMask && (n0 + r) < (mbase + t2)) sval = 0.0f;
                        pk.s[t2] = f2bf(sval);
                    }
                    *(uint2*)((char*)Ps + aswz(r, (m4 * 16 + (l >> 4) * 4) * 2)) = pk.u;
                }
            }
            WAITL();
            __builtin_amdgcn_sched_barrier(0);
            __builtin_amdgcn_s_setprio(1);
#pragma unroll
            for (int kc = 0; kc < 2; ++kc) {
                v8s ap[2];
#pragma unroll
                for (int rg = 0; rg < 2; ++rg) {
                    const int r = w * 32 + rg * 16 + (l & 15);
                    ap[rg] = *(const v8s*)((char*)Ps + aswz(r, kc * 64 + (l >> 4) * 16));
                }
#pragma unroll
                for (int dt = 0; dt < 4; ++dt) {
                    const int d = dt * 16 + (l & 15);
                    v8s bv = *(const v8s*)(VtsB + aswz(d, kc * 64 + (l >> 4) * 16));
#pragma unroll
                    for (int rg = 0; rg < 2; ++rg)
                        oacc[rg][dt] = __builtin_amdgcn_mfma_f32_16x16x32_bf16(bv, ap[rg], oacc[rg][dt], 0, 0, 0);
                }
            }
            __builtin_amdgcn_s_setprio(0);
        }
    }
    float psum = 0.0f, pssq = 0.0f;
#pragma unroll
    for (int rg = 0; rg < 2; ++rg) {
        const int row = n0 + w * 32 + rg * 16 + (l & 15);
#pragma unroll
        for (int dt = 0; dt < 4; ++dt) {
            const float a0 = oacc[rg][dt][0], a1 = oacc[rg][dt][1];
            const float a2 = oacc[rg][dt][2], a3 = oacc[rg][dt][3];
            short4 o4 = make_short4(f2bf(a0), f2bf(a1), f2bf(a2), f2bf(a3));
            *(short4*)(O + (size_t)(b * NSEQ + row) * DM + h * HD + dt * 16 + (l >> 4) * 4) = o4;
            psum += a0 + a1 + a2 + a3;
            pssq += a0 * a0 + a1 * a1 + a2 * a2 + a3 * a3;
        }
    }
    __syncthreads();
    float* red = (float*)Ks;
    red[tid] = psum; red[256 + tid] = pssq;
    __syncthreads();
    for (int s = 128; s > 0; s >>= 1) {
        if (tid < s) { red[tid] += red[tid + s]; red[256 + tid] += red[256 + tid + s]; }
        __syncthreads();
    }
    if (tid == 0) {
        partial[(bh * 8 + qq) * 2]     = red[0];
        partial[(bh * 8 + qq) * 2 + 1] = red[256];
    }
}

extern "C" void kernel_launch(void* const* d_in, const int* in_sizes, int n_in,
                              void* d_out, int out_size, void* d_ws, size_t ws_size,
                              hipStream_t stream) {
    const float* X       = (const float*)d_in[0];
    const float* ts      = (const float*)d_in[1];
    const float* W_qkv   = (const float*)d_in[2];
    const float* W_gamma = (const float*)d_in[3];
    const float* W_gated = (const float*)d_in[4];
    const float* W_out   = (const float*)d_in[5];
    float* out = (float*)d_out;

    char* ws = (char*)d_ws;
    short*  Xb    = (short*)(ws + 0);              //  8 MB (tiled bf16)
    short*  Wtq   = (short*)(ws + 8388608);        //  6 MB
    short*  Wtg   = (short*)(ws + 14680064);       //  2 MB
    short*  Wto   = (short*)(ws + 16777216);       //  2 MB
    short*  Qb    = (short*)(ws + 18874368);       //  8 MB
    short*  Kb    = (short*)(ws + 27262976);       //  8 MB
    short*  Vtb   = (short*)(ws + 35651584);       //  8 MB
    float*  logb  = (float*)(ws + 44040192);       //  256 KB
    float*  logbT = (float*)(ws + 44302336);       //  256 KB
    float4* tbl   = (float4*)(ws + 44564480);      //  2 MB
    short*  Oatt  = (short*)(ws + 46661632);       //  8 MB (bf16)
    float*  partial = (float*)(ws + 55050240);     //  4 KB
    short*  Gb    = (short*)(ws + 55054336);       //  8 MB (dedicated; no Xb race)
    short*  qkvb  = (short*)(ws + 63442944);       // 24 MB

    prep_inputs<<<2048, 256, 0, stream>>>(X, ts, W_qkv, W_gamma, W_gated, W_out,
                                          Wtq, Wtg, Wto, logb, Xb, tbl);
    scan_kernel<<<16, 256, 0, stream>>>(logb, logbT);
    gemm_tt<1><<<dim3(24, 32), 256, 0, stream>>>(Xb, Wtq, qkvb, 3072, nullptr, nullptr);
    prep<<<dim3(16, 64), 256, 0, stream>>>(qkvb, tbl, Qb, Kb, Vtb);
    attn6<<<512, 256, 0, stream>>>(Qb, Kb, Vtb, logbT, Oatt, partial);
    gemm_tt<2><<<dim3(8, 32), 256, 0, stream>>>(Xb, Wtg, Gb, 1024, Oatt, partial);
    gemm_tt<0><<<dim3(8, 32), 256, 0, stream>>>(Gb, Wto, out, 1024, nullptr, nullptr);
}